// Round 4
// baseline (135.842 us; speedup 1.0000x reference)
//
#include <hip/hip_runtime.h>
#include <cfloat>
#include <cmath>

// x[B,W,L], shapelets[N,L], cls_w[1,N], cls_b[1]
constexpr int B = 64;
constexpr int W = 256;
constexpr int N = 128;
constexpr int L = 64;

// Monotone-DECREASING float->uint encoding: smaller float -> larger key.
// Init value 0 decodes above every real float, so atomicMax computes min.
__device__ __forceinline__ unsigned enc_min(float f) {
  unsigned u = __float_as_uint(f);
  return (u & 0x80000000u) ? u : ~(u | 0x80000000u);
}
__device__ __forceinline__ float dec_min(unsigned m) {
  unsigned k = ~m;  // standard ascending key
  return (k & 0x80000000u) ? __uint_as_float(k & 0x7FFFFFFFu)
                           : __uint_as_float(~k);
}

// ---------------------------------------------------------------------------
// Fused kernel: grid = B*16 blocks of 256 (= 128 shapelets x 2 window-slots).
// Each block handles 16 windows of one b:
//   min_w ( ||x_w||^2 - 2 <x_w, s_n> )   -> atomicMax into part[b][n]
// The last block to finish runs the head: +||s_n||^2, sqrt, dot(cls_w),
// sigmoid -> out[0..63].  All part[] traffic is device-scope atomic (coherent
// across XCDs); counter gives last-block detection.
// ---------------------------------------------------------------------------
__global__ __launch_bounds__(256) void shapelet_fused_kernel(
    const float* __restrict__ x, const float* __restrict__ shp,
    const float* __restrict__ cls_w, const float* __restrict__ cls_b,
    unsigned* __restrict__ part, unsigned* __restrict__ counter,
    float* __restrict__ out) {
  constexpr int WPB = 16;
  __shared__ float xs[WPB * L];  // 4 KB
  __shared__ float xnorm_s[WPB];
  __shared__ float comb[N];
  __shared__ unsigned last_flag;

  const int b = blockIdx.x >> 4;
  const int c = blockIdx.x & 15;
  const int tid = threadIdx.x;
  const int n = tid & (N - 1);  // shapelet owned by this thread
  const int wslot = tid >> 7;   // 0/1: which half of the 16 windows

  // --- Stage x[b, c*16:(c+1)*16, :]: one float4/thread, fused ||x_w||^2
  // via 16-lane shuffle reduce (16 float4 per window).
  {
    const float4* xg =
        (const float4*)(x + ((size_t)b * W + (size_t)c * WPB) * L);
    float4 v = xg[tid];
    ((float4*)xs)[tid] = v;
    float p = v.x * v.x + v.y * v.y + v.z * v.z + v.w * v.w;
    p += __shfl_xor(p, 8, 16);
    p += __shfl_xor(p, 4, 16);
    p += __shfl_xor(p, 2, 16);
    p += __shfl_xor(p, 1, 16);
    if ((tid & 15) == 0) xnorm_s[tid >> 4] = p;
  }

  // --- Shapelet row n -> 64 VGPRs (32 KB table, L1/L2 resident).
  float s[L];
  {
    const float4* sg = (const float4*)(shp + (size_t)n * L);
#pragma unroll
    for (int i = 0; i < L / 4; ++i) {
      float4 v = sg[i];
      s[4 * i + 0] = v.x;
      s[4 * i + 1] = v.y;
      s[4 * i + 2] = v.z;
      s[4 * i + 3] = v.w;
    }
  }

  __syncthreads();

  // --- min over this slot's 8 windows of (xnorm_w - 2*dot).
  float best = FLT_MAX;
  const int w0 = wslot * 8;
  for (int wi = 0; wi < 8; ++wi) {
    const float* xr = xs + (size_t)(w0 + wi) * L;
    float a0 = 0.f, a1 = 0.f, a2 = 0.f, a3 = 0.f;  // 4 chains for ILP
#pragma unroll
    for (int l = 0; l < L; l += 4) {
      // Wave-uniform address -> conflict-free LDS broadcast.
      float4 xv = *(const float4*)(xr + l);
      a0 = fmaf(xv.x, s[l + 0], a0);
      a1 = fmaf(xv.y, s[l + 1], a1);
      a2 = fmaf(xv.z, s[l + 2], a2);
      a3 = fmaf(xv.w, s[l + 3], a3);
    }
    best = fminf(best, fmaf(-2.f, (a0 + a1) + (a2 + a3), xnorm_s[w0 + wi]));
  }

  // --- Combine window-slots, then device-scope atomicMax into part[b][n].
  __syncthreads();
  if (wslot == 1) comb[n] = best;
  __syncthreads();
  if (wslot == 0) {
    atomicMax(&part[(size_t)b * N + n], enc_min(fminf(best, comb[n])));
  }

  // --- Last-block detection (release: drain our atomics first).
  __threadfence();
  if (tid == 0) {
    unsigned old = atomicAdd(counter, 1u);
    last_flag = (old == (unsigned)(B * 16 - 1)) ? 1u : 0u;
  }
  __syncthreads();
  if (last_flag == 0) return;
  __threadfence();  // acquire

  // ---------------- Head (single block, 256 threads) ----------------
  __shared__ float sn_s[N], w_s[N], psum[256];
  if (tid < N) {
    const float4* sg = (const float4*)(shp + (size_t)tid * L);
    float sn = 0.f;
#pragma unroll
    for (int i = 0; i < L / 4; ++i) {
      float4 v = sg[i];
      sn = fmaf(v.x, v.x, sn);
      sn = fmaf(v.y, v.y, sn);
      sn = fmaf(v.z, v.z, sn);
      sn = fmaf(v.w, v.w, sn);
    }
    sn_s[tid] = sn;
    w_s[tid] = cls_w[tid];
  }
  __syncthreads();

  // Thread t: b = t>>2, quarter q = t&3 -> 32 shapelets each.
  {
    const int bb = tid >> 2, q = tid & 3;
    float acc = 0.f;
#pragma unroll 4
    for (int j = 0; j < 32; ++j) {
      const int nn = q * 32 + j;
      // Coherent read via no-op RMW on the same atomic path as writers.
      unsigned m = atomicMax(&part[(size_t)bb * N + nn], 0u);
      float d2 = fmaxf(dec_min(m) + sn_s[nn], 0.f);
      acc = fmaf(sqrtf(d2), w_s[nn], acc);
    }
    psum[tid] = acc;
  }
  __syncthreads();
  if (tid < B) {
    float z = psum[4 * tid] + psum[4 * tid + 1] + psum[4 * tid + 2] +
              psum[4 * tid + 3] + cls_b[0];
    out[tid] = 1.0f / (1.0f + expf(-z));
  }
}

// ---------------------------------------------------------------------------
// Fallback (generic NCHUNKS, two kernels) — only if ws_size is tiny.
// ---------------------------------------------------------------------------
template <int NCHUNKS>
__global__ __launch_bounds__(256) void shapelet_min_kernel(
    const float* __restrict__ x, const float* __restrict__ shp,
    float* __restrict__ part) {
  constexpr int WPB = W / NCHUNKS;
  constexpr int NV4 = WPB * L / 4;
  __shared__ float xs[WPB * L];
  __shared__ float xnorm_s[WPB];
  __shared__ float comb[N];

  const int b = blockIdx.x / NCHUNKS;
  const int c = blockIdx.x % NCHUNKS;
  const int tid = threadIdx.x;
  const int n = tid & (N - 1);
  const int wslot = tid >> 7;

  if (tid < WPB) xnorm_s[tid] = 0.f;
  __syncthreads();
  {
    const float4* xg =
        (const float4*)(x + ((size_t)b * W + (size_t)c * WPB) * L);
    for (int i = tid; i < NV4; i += 256) {
      float4 v = xg[i];
      ((float4*)xs)[i] = v;
      atomicAdd(&xnorm_s[i >> 4],
                v.x * v.x + v.y * v.y + v.z * v.z + v.w * v.w);
    }
  }
  float s[L];
  {
    const float4* sg = (const float4*)(shp + (size_t)n * L);
#pragma unroll
    for (int i = 0; i < L / 4; ++i) {
      float4 v = sg[i];
      s[4 * i + 0] = v.x; s[4 * i + 1] = v.y;
      s[4 * i + 2] = v.z; s[4 * i + 3] = v.w;
    }
  }
  __syncthreads();
  float best = FLT_MAX;
  const int w0 = wslot * (WPB / 2);
  for (int wi = 0; wi < WPB / 2; ++wi) {
    const float* xr = xs + (size_t)(w0 + wi) * L;
    float a0 = 0.f, a1 = 0.f, a2 = 0.f, a3 = 0.f;
#pragma unroll
    for (int l = 0; l < L; l += 4) {
      float4 xv = *(const float4*)(xr + l);
      a0 = fmaf(xv.x, s[l + 0], a0);
      a1 = fmaf(xv.y, s[l + 1], a1);
      a2 = fmaf(xv.z, s[l + 2], a2);
      a3 = fmaf(xv.w, s[l + 3], a3);
    }
    best = fminf(best, fmaf(-2.f, (a0 + a1) + (a2 + a3), xnorm_s[w0 + wi]));
  }
  __syncthreads();
  if (wslot == 1) comb[n] = best;
  __syncthreads();
  if (wslot == 0)
    part[((size_t)b * NCHUNKS + c) * N + n] = fminf(best, comb[n]);
}

template <int NCHUNKS>
__global__ __launch_bounds__(128) void shapelet_head_kernel(
    const float* __restrict__ part, const float* __restrict__ shp,
    const float* __restrict__ cls_w, const float* __restrict__ cls_b,
    float* __restrict__ out) {
  const int b = blockIdx.x;
  const int n = threadIdx.x;
  float m = FLT_MAX;
#pragma unroll
  for (int c = 0; c < NCHUNKS; ++c)
    m = fminf(m, part[((size_t)b * NCHUNKS + c) * N + n]);
  float sn = 0.f;
  {
    const float4* sg = (const float4*)(shp + (size_t)n * L);
#pragma unroll
    for (int i = 0; i < L / 4; ++i) {
      float4 v = sg[i];
      sn = fmaf(v.x, v.x, sn);
      sn = fmaf(v.y, v.y, sn);
      sn = fmaf(v.z, v.z, sn);
      sn = fmaf(v.w, v.w, sn);
    }
  }
  float v = sqrtf(fmaxf(m + sn, 0.f)) * cls_w[n];
#pragma unroll
  for (int off = 32; off > 0; off >>= 1) v += __shfl_down(v, off, 64);
  __shared__ float red[2];
  if ((n & 63) == 0) red[n >> 6] = v;
  __syncthreads();
  if (n == 0) {
    float z = red[0] + red[1] + cls_b[0];
    out[b] = 1.0f / (1.0f + expf(-z));
  }
}

extern "C" void kernel_launch(void* const* d_in, const int* in_sizes, int n_in,
                              void* d_out, int out_size, void* d_ws,
                              size_t ws_size, hipStream_t stream) {
  const float* x = (const float*)d_in[0];      // [B, W, L]
  const float* shp = (const float*)d_in[1];    // [N, L]
  const float* cls_w = (const float*)d_in[2];  // [1, N]
  const float* cls_b = (const float*)d_in[3];  // [1]
  float* out = (float*)d_out;                  // [B, 1]

  const size_t fused_bytes = (size_t)(B * N + 1) * sizeof(unsigned);  // 33 KB
  if (ws_size >= fused_bytes) {
    unsigned* part = (unsigned*)d_ws;        // [B*N] encoded mins
    unsigned* counter = part + (size_t)B * N;
    // Zero part (0 decodes to +inf under enc_min) and counter in one node.
    hipMemsetAsync(d_ws, 0, fused_bytes, stream);
    shapelet_fused_kernel<<<B * 16, 256, 0, stream>>>(x, shp, cls_w, cls_b,
                                                      part, counter, out);
  } else {
    // Degenerate fallback: NCHUNKS=1 two-kernel path (needs 32 KB).
    float* part = (float*)d_ws;
    shapelet_min_kernel<1><<<B, 256, 0, stream>>>(x, shp, part);
    shapelet_head_kernel<1><<<B, 128, 0, stream>>>(part, shp, cls_w, cls_b,
                                                   out);
  }
}

// Round 5
// 124.591 us; speedup vs baseline: 1.0903x; 1.0903x over previous
//
#include <hip/hip_runtime.h>
#include <cfloat>
#include <cmath>

// x[B,W,L], shapelets[N,L], cls_w[1,N], cls_b[1]
constexpr int B = 64;
constexpr int W = 256;
constexpr int N = 128;
constexpr int L = 64;
constexpr int NC = 16;        // window-chunks per batch element
constexpr int WPB = W / NC;   // 16 windows per block

// ---------------------------------------------------------------------------
// Kernel 1: per-(b, chunk) compute  min_w ( ||x_w||^2 - 2 <x_w, s_n> )  for
// all 128 shapelets. ||s_n||^2 added in kernel 2 (min commutes with it).
// grid = B*NC, block = 256 (= 128 shapelets x 2 window-slots).
//
// CRITICAL (R4 post-mortem): the shapelet row must live in NAMED registers.
// A `float s[64]` alloca was refused promotion (VGPR_Count=48 -> scratch
// spill -> 77 us kernel). 16 named float4s cannot spill that way.
// ---------------------------------------------------------------------------
__global__ __launch_bounds__(256, 4) void shapelet_min_kernel(
    const float* __restrict__ x, const float* __restrict__ shp,
    float* __restrict__ part) {
  __shared__ float xs[WPB * L];   // 4 KB
  __shared__ float xnorm_s[WPB];
  __shared__ float comb[N];

  const int b = blockIdx.x >> 4;
  const int c = blockIdx.x & 15;
  const int tid = threadIdx.x;
  const int n = tid & (N - 1);    // shapelet owned by this thread
  const int wslot = tid >> 7;     // 0/1: first/second 8 windows

  // --- Stage x[b, c*16:(c+1)*16, :]: one float4/thread, fused ||x_w||^2
  // via 16-lane shuffle reduce (16 float4 per window).
  {
    const float4* xg =
        (const float4*)(x + ((size_t)b * W + (size_t)c * WPB) * L);
    float4 v = xg[tid];
    ((float4*)xs)[tid] = v;
    float p = v.x * v.x + v.y * v.y + v.z * v.z + v.w * v.w;
    p += __shfl_xor(p, 8, 16);
    p += __shfl_xor(p, 4, 16);
    p += __shfl_xor(p, 2, 16);
    p += __shfl_xor(p, 1, 16);
    if ((tid & 15) == 0) xnorm_s[tid >> 4] = p;
  }

  // --- Shapelet row n in 16 NAMED float4 registers (64 VGPRs).
  const float4* sg = (const float4*)(shp + (size_t)n * L);
  const float4 s0 = sg[0], s1 = sg[1], s2 = sg[2], s3 = sg[3];
  const float4 s4 = sg[4], s5 = sg[5], s6 = sg[6], s7 = sg[7];
  const float4 s8 = sg[8], s9 = sg[9], s10 = sg[10], s11 = sg[11];
  const float4 s12 = sg[12], s13 = sg[13], s14 = sg[14], s15 = sg[15];

  __syncthreads();

  // --- min over this slot's 8 windows of (xnorm_w - 2*dot(x_w, s_n)).
  float best = FLT_MAX;
  const int w0 = wslot * (WPB / 2);
  for (int wi = 0; wi < WPB / 2; ++wi) {
    // Wave-uniform base address -> every read is a conflict-free broadcast.
    const float4* xr = (const float4*)(xs + (size_t)(w0 + wi) * L);
    float a0 = 0.f, a1 = 0.f, a2 = 0.f, a3 = 0.f;  // 4 chains for ILP
#define SHP_STEP(K, SV)                  \
  {                                      \
    float4 xv = xr[K];                   \
    a0 = fmaf(xv.x, (SV).x, a0);         \
    a1 = fmaf(xv.y, (SV).y, a1);         \
    a2 = fmaf(xv.z, (SV).z, a2);         \
    a3 = fmaf(xv.w, (SV).w, a3);         \
  }
    SHP_STEP(0, s0)   SHP_STEP(1, s1)   SHP_STEP(2, s2)   SHP_STEP(3, s3)
    SHP_STEP(4, s4)   SHP_STEP(5, s5)   SHP_STEP(6, s6)   SHP_STEP(7, s7)
    SHP_STEP(8, s8)   SHP_STEP(9, s9)   SHP_STEP(10, s10) SHP_STEP(11, s11)
    SHP_STEP(12, s12) SHP_STEP(13, s13) SHP_STEP(14, s14) SHP_STEP(15, s15)
#undef SHP_STEP
    best = fminf(best, fmaf(-2.f, (a0 + a1) + (a2 + a3), xnorm_s[w0 + wi]));
  }

  // --- Combine the two window-slots per shapelet, write part[b][c][n].
  __syncthreads();
  if (wslot == 1) comb[n] = best;
  __syncthreads();
  if (wslot == 0) {
    part[((size_t)b * NC + c) * N + n] = fminf(best, comb[n]);
  }
}

// ---------------------------------------------------------------------------
// Kernel 2: min over chunks -> +||s_n||^2 -> sqrt -> dot(cls_w) -> sigmoid.
// grid = B, block = 128 (one thread per shapelet). No allocas anywhere.
// ---------------------------------------------------------------------------
__global__ __launch_bounds__(128) void shapelet_head_kernel(
    const float* __restrict__ part, const float* __restrict__ shp,
    const float* __restrict__ cls_w, const float* __restrict__ cls_b,
    float* __restrict__ out) {
  const int b = blockIdx.x;
  const int n = threadIdx.x;  // 0..127

  float m = FLT_MAX;
#pragma unroll
  for (int c = 0; c < NC; ++c)
    m = fminf(m, part[((size_t)b * NC + c) * N + n]);

  // ||s_n||^2: accumulate straight out of float4 loads (no array).
  float sn = 0.f;
  {
    const float4* sg = (const float4*)(shp + (size_t)n * L);
#pragma unroll
    for (int i = 0; i < L / 4; ++i) {
      float4 v = sg[i];
      sn = fmaf(v.x, v.x, sn);
      sn = fmaf(v.y, v.y, sn);
      sn = fmaf(v.z, v.z, sn);
      sn = fmaf(v.w, v.w, sn);
    }
  }

  float d2 = fmaxf(m + sn, 0.f);  // guard fp rounding before sqrt
  float v = sqrtf(d2) * cls_w[n];

  // Sum over 128 threads: wave64 shuffle reduce, combine 2 waves via LDS.
#pragma unroll
  for (int off = 32; off > 0; off >>= 1) v += __shfl_down(v, off, 64);

  __shared__ float red[2];
  if ((n & 63) == 0) red[n >> 6] = v;
  __syncthreads();
  if (n == 0) {
    float z = red[0] + red[1] + cls_b[0];
    out[b] = 1.0f / (1.0f + expf(-z));
  }
}

extern "C" void kernel_launch(void* const* d_in, const int* in_sizes, int n_in,
                              void* d_out, int out_size, void* d_ws,
                              size_t ws_size, hipStream_t stream) {
  const float* x = (const float*)d_in[0];      // [B, W, L]
  const float* shp = (const float*)d_in[1];    // [N, L]
  const float* cls_w = (const float*)d_in[2];  // [1, N]
  const float* cls_b = (const float*)d_in[3];  // [1]
  float* out = (float*)d_out;                  // [B, 1]
  float* part = (float*)d_ws;                  // [B, NC, N] fp32 (128 KB)

  shapelet_min_kernel<<<B * NC, 256, 0, stream>>>(x, shp, part);
  shapelet_head_kernel<<<B, 128, 0, stream>>>(part, shp, cls_w, cls_b, out);
}

// Round 6
// 71.319 us; speedup vs baseline: 1.9047x; 1.7470x over previous
//
#include <hip/hip_runtime.h>
#include <cfloat>
#include <cmath>

// x[B,W,L], shapelets[N,L], cls_w[1,N], cls_b[1]
constexpr int B = 64;
constexpr int W = 256;
constexpr int N = 128;
constexpr int L = 64;
constexpr int NC = 16;        // window-chunks per batch element
constexpr int WPB = W / NC;   // 16 windows per block

// ---------------------------------------------------------------------------
// Kernel 1: per-(b, chunk) compute  min_w ( ||x_w||^2 - 2 <x_w, s_n> )  for
// all 128 shapelets. ||s_n||^2 added in kernel 2 (min commutes with it).
// grid = B*NC, block = 256.
//
// R4/R5 post-mortem: 64 floats/thread of shapelet data ALWAYS spills (the
// backend targets 8 waves/EU -> 64-VGPR cap; scratch thrashing cost 62-77us).
// Fix: thread PAIR per shapelet. n = tid>>1, half = tid&1; each thread holds
// only HALF a shapelet row (8 named float4 = 32 VGPRs) and computes half-dots
// over all 16 windows; halves combine via __shfl_xor(.,1) (DPP, ~free).
// Peak live regs ~50 < 64 -> no spill at any occupancy target.
// ---------------------------------------------------------------------------
__global__ __launch_bounds__(256) void shapelet_min_kernel(
    const float* __restrict__ x, const float* __restrict__ shp,
    float* __restrict__ part) {
  __shared__ float xs[WPB * L];   // 4 KB
  __shared__ float xnorm_s[WPB];

  const int b = blockIdx.x >> 4;
  const int c = blockIdx.x & 15;
  const int tid = threadIdx.x;
  const int n = tid >> 1;         // shapelet owned by this thread pair
  const int half = tid & 1;       // which 32-element half of the row

  // --- Stage x[b, c*16:(c+1)*16, :]: one float4/thread, fused ||x_w||^2
  // via 16-lane shuffle reduce (16 float4 per window).
  {
    const float4* xg =
        (const float4*)(x + ((size_t)b * W + (size_t)c * WPB) * L);
    float4 v = xg[tid];
    ((float4*)xs)[tid] = v;
    float p = v.x * v.x + v.y * v.y + v.z * v.z + v.w * v.w;
    p += __shfl_xor(p, 8, 16);
    p += __shfl_xor(p, 4, 16);
    p += __shfl_xor(p, 2, 16);
    p += __shfl_xor(p, 1, 16);
    if ((tid & 15) == 0) xnorm_s[tid >> 4] = p;
  }

  // --- Half shapelet row: 8 NAMED float4 (32 VGPRs). No array, no spill.
  const float4* sg = (const float4*)(shp + (size_t)n * L + half * 32);
  const float4 s0 = sg[0], s1 = sg[1], s2 = sg[2], s3 = sg[3];
  const float4 s4 = sg[4], s5 = sg[5], s6 = sg[6], s7 = sg[7];

  __syncthreads();

  // --- min over ALL 16 windows of (xnorm_w - 2*dot(x_w, s_n)).
  float best = FLT_MAX;
  for (int w = 0; w < WPB; ++w) {
    // Two wave-uniform addresses per read (half=0/1) -> conflict-free.
    const float4* xr = (const float4*)(xs + (size_t)w * L + half * 32);
    float a0 = 0.f, a1 = 0.f, a2 = 0.f, a3 = 0.f;  // 4 chains for ILP
#define SHP_STEP(K, SV)              \
  {                                  \
    float4 xv = xr[K];               \
    a0 = fmaf(xv.x, (SV).x, a0);     \
    a1 = fmaf(xv.y, (SV).y, a1);     \
    a2 = fmaf(xv.z, (SV).z, a2);     \
    a3 = fmaf(xv.w, (SV).w, a3);     \
  }
    SHP_STEP(0, s0) SHP_STEP(1, s1) SHP_STEP(2, s2) SHP_STEP(3, s3)
    SHP_STEP(4, s4) SHP_STEP(5, s5) SHP_STEP(6, s6) SHP_STEP(7, s7)
#undef SHP_STEP
    float d = (a0 + a1) + (a2 + a3);   // half-dot
    d += __shfl_xor(d, 1, 64);         // combine halves (lane pair, DPP)
    best = fminf(best, fmaf(-2.f, d, xnorm_s[w]));
  }

  // --- Even lane of each pair writes part[b][c][n].
  if (half == 0) {
    part[((size_t)b * NC + c) * N + n] = best;
  }
}

// ---------------------------------------------------------------------------
// Kernel 2: min over chunks -> +||s_n||^2 -> sqrt -> dot(cls_w) -> sigmoid.
// grid = B, block = 128 (one thread per shapelet). No allocas anywhere.
// ---------------------------------------------------------------------------
__global__ __launch_bounds__(128) void shapelet_head_kernel(
    const float* __restrict__ part, const float* __restrict__ shp,
    const float* __restrict__ cls_w, const float* __restrict__ cls_b,
    float* __restrict__ out) {
  const int b = blockIdx.x;
  const int n = threadIdx.x;  // 0..127

  float m = FLT_MAX;
#pragma unroll
  for (int c = 0; c < NC; ++c)
    m = fminf(m, part[((size_t)b * NC + c) * N + n]);

  // ||s_n||^2: accumulate straight out of float4 loads (no array).
  float sn = 0.f;
  {
    const float4* sg = (const float4*)(shp + (size_t)n * L);
#pragma unroll
    for (int i = 0; i < L / 4; ++i) {
      float4 v = sg[i];
      sn = fmaf(v.x, v.x, sn);
      sn = fmaf(v.y, v.y, sn);
      sn = fmaf(v.z, v.z, sn);
      sn = fmaf(v.w, v.w, sn);
    }
  }

  float d2 = fmaxf(m + sn, 0.f);  // guard fp rounding before sqrt
  float v = sqrtf(d2) * cls_w[n];

  // Sum over 128 threads: wave64 shuffle reduce, combine 2 waves via LDS.
#pragma unroll
  for (int off = 32; off > 0; off >>= 1) v += __shfl_down(v, off, 64);

  __shared__ float red[2];
  if ((n & 63) == 0) red[n >> 6] = v;
  __syncthreads();
  if (n == 0) {
    float z = red[0] + red[1] + cls_b[0];
    out[b] = 1.0f / (1.0f + expf(-z));
  }
}

extern "C" void kernel_launch(void* const* d_in, const int* in_sizes, int n_in,
                              void* d_out, int out_size, void* d_ws,
                              size_t ws_size, hipStream_t stream) {
  const float* x = (const float*)d_in[0];      // [B, W, L]
  const float* shp = (const float*)d_in[1];    // [N, L]
  const float* cls_w = (const float*)d_in[2];  // [1, N]
  const float* cls_b = (const float*)d_in[3];  // [1]
  float* out = (float*)d_out;                  // [B, 1]
  float* part = (float*)d_ws;                  // [B, NC, N] fp32 (128 KB)

  shapelet_min_kernel<<<B * NC, 256, 0, stream>>>(x, shp, part);
  shapelet_head_kernel<<<B, 128, 0, stream>>>(part, shp, cls_w, cls_b, out);
}